// Round 4
// baseline (254.376 us; speedup 1.0000x reference)
//
#include <hip/hip_runtime.h>
#include <hip/hip_bf16.h>

// out[n,c,h,w] = sum_{5x5 in-bounds taps} exp(-0.5*||xyz_nbr - xyz_ctr||^2)
//                * mask_nbr * softmax[n,c,nbr]
// Zero-padded softmax => OOB taps contribute 0; clamped loads under zero
// weights are safe (finite garbage * 0.0f).
//
// R4: same as R3 (4 px/thread x 5 ch/thread) but 1D grid ONLY — the harness's
// graph-replay timing path mishandled gridDim.y (channels 5..19 stayed poison
// post-timing). cg interleaved in low bits so blocks sharing a pixel window
// are co-scheduled (xyz/mask L2 reuse).

#define H_DIM 64
#define W_DIM 2048
#define C_DIM 20
#define N_DIM 8
#define HW (H_DIM * W_DIM)
#define C_GROUPS 4
#define C_PER 5            // channels per thread

__global__ __launch_bounds__(256) void lcx_kernel(
    const float* __restrict__ xyz,
    const float* __restrict__ sm,
    const int*  __restrict__ mask,
    float* __restrict__ out)
{
    const int bid = blockIdx.x;
    const int cg  = bid & (C_GROUPS - 1);                    // 0..3
    const int tid = (bid >> 2) * blockDim.x + threadIdx.x;   // pixel-thread id, 0..262143
    const int w  = (tid & (W_DIM / 4 - 1)) << 2;             // 0,4,...,2044
    const int hn = tid >> 9;                                 // /(W/4)
    const int h  = hn & (H_DIM - 1);
    const int n  = hn >> 6;

    const float* xyzn  = xyz  + (size_t)n * 3 * HW;
    const int*   maskn = mask + (size_t)n * HW;
    const float* smn   = sm   + ((size_t)n * C_DIM + cg * C_PER) * HW;
    float*       outn  = out  + ((size_t)n * C_DIM + cg * C_PER) * HW;

    const int ctr = h * W_DIM + w;

    // center coords for the 4 pixels (vector load)
    const float4 cxv = *(const float4*)(xyzn + 0 * HW + ctr);
    const float4 cyv = *(const float4*)(xyzn + 1 * HW + ctr);
    const float4 czv = *(const float4*)(xyzn + 2 * HW + ctr);
    const float cx[4] = {cxv.x, cxv.y, cxv.z, cxv.w};
    const float cy[4] = {cyv.x, cyv.y, cyv.z, cyv.w};
    const float cz[4] = {czv.x, czv.y, czv.z, czv.w};

    float4 acc[C_PER];
    #pragma unroll
    for (int c = 0; c < C_PER; ++c) acc[c] = make_float4(0.f, 0.f, 0.f, 0.f);

    // clamped column bases; columns covered: [w-2 .. w+5]
    const int b0 = (w >= 2) ? (w - 2) : 0;                        // float2 (8B-aligned)
    const int b1 = w;                                             // float4 (16B-aligned)
    const int b2 = (w + 4 <= W_DIM - 2) ? (w + 4) : (W_DIM - 2);  // float2

    #pragma unroll
    for (int di = 0; di < 5; ++di) {
        const int hi = h + di - 2;
        if ((unsigned)hi >= (unsigned)H_DIM) continue;   // block-uniform skip
        const int rb = hi * W_DIM;

        // xyz row segments: 8 columns [w-2 .. w+5] per plane
        float xs[8], ys[8], zs[8];
        {
            const float* px = xyzn + 0 * HW + rb;
            const float2 t0 = *(const float2*)(px + b0);
            const float4 t1 = *(const float4*)(px + b1);
            const float2 t2 = *(const float2*)(px + b2);
            xs[0]=t0.x; xs[1]=t0.y; xs[2]=t1.x; xs[3]=t1.y;
            xs[4]=t1.z; xs[5]=t1.w; xs[6]=t2.x; xs[7]=t2.y;
        }
        {
            const float* py = xyzn + 1 * HW + rb;
            const float2 t0 = *(const float2*)(py + b0);
            const float4 t1 = *(const float4*)(py + b1);
            const float2 t2 = *(const float2*)(py + b2);
            ys[0]=t0.x; ys[1]=t0.y; ys[2]=t1.x; ys[3]=t1.y;
            ys[4]=t1.z; ys[5]=t1.w; ys[6]=t2.x; ys[7]=t2.y;
        }
        {
            const float* pz = xyzn + 2 * HW + rb;
            const float2 t0 = *(const float2*)(pz + b0);
            const float4 t1 = *(const float4*)(pz + b1);
            const float2 t2 = *(const float2*)(pz + b2);
            zs[0]=t0.x; zs[1]=t0.y; zs[2]=t1.x; zs[3]=t1.y;
            zs[4]=t1.z; zs[5]=t1.w; zs[6]=t2.x; zs[7]=t2.y;
        }
        int ms[8];
        {
            const int* pm = maskn + rb;
            const int2 m0 = *(const int2*)(pm + b0);
            const int4 m1 = *(const int4*)(pm + b1);
            const int2 m2 = *(const int2*)(pm + b2);
            ms[0]=m0.x; ms[1]=m0.y; ms[2]=m1.x; ms[3]=m1.y;
            ms[4]=m1.z; ms[5]=m1.w; ms[6]=m2.x; ms[7]=m2.y;
        }

        // 20 weights for this row (4 pixels x 5 dj taps)
        float wgt[4][5];
        #pragma unroll
        for (int p = 0; p < 4; ++p) {
            #pragma unroll
            for (int dj = 0; dj < 5; ++dj) {
                const int s = p + dj;                     // seg index, col = w-2+s
                const float dx = xs[s] - cx[p];
                const float dy = ys[s] - cy[p];
                const float dz = zs[s] - cz[p];
                const float d2 = fmaf(dx, dx, fmaf(dy, dy, dz * dz));
                const bool ok = ((unsigned)(w - 2 + s) < (unsigned)W_DIM) && (ms[s] != 0);
                wgt[p][dj] = ok ? __expf(-0.5f * d2) : 0.0f;
            }
        }

        // 5 channels: 3 wide loads + 20 FMAs each (independent across c -> ILP)
        #pragma unroll
        for (int c = 0; c < C_PER; ++c) {
            const float* pr = smn + (size_t)c * HW + rb;
            const float2 f0 = *(const float2*)(pr + b0);
            const float4 f1 = *(const float4*)(pr + b1);
            const float2 f2 = *(const float2*)(pr + b2);
            float fs[8];
            fs[0]=f0.x; fs[1]=f0.y; fs[2]=f1.x; fs[3]=f1.y;
            fs[4]=f1.z; fs[5]=f1.w; fs[6]=f2.x; fs[7]=f2.y;

            #pragma unroll
            for (int p = 0; p < 4; ++p) {
                float a = (p == 0) ? acc[c].x : (p == 1) ? acc[c].y
                        : (p == 2) ? acc[c].z : acc[c].w;
                #pragma unroll
                for (int dj = 0; dj < 5; ++dj)
                    a = fmaf(wgt[p][dj], fs[p + dj], a);
                if      (p == 0) acc[c].x = a;
                else if (p == 1) acc[c].y = a;
                else if (p == 2) acc[c].z = a;
                else             acc[c].w = a;
            }
        }
    }

    #pragma unroll
    for (int c = 0; c < C_PER; ++c)
        *(float4*)(outn + (size_t)c * HW + ctr) = acc[c];
}

extern "C" void kernel_launch(void* const* d_in, const int* in_sizes, int n_in,
                              void* d_out, int out_size, void* d_ws, size_t ws_size,
                              hipStream_t stream)
{
    const float* xyz  = (const float*)d_in[0];
    const float* sm   = (const float*)d_in[1];
    const int*   mask = (const int*)d_in[2];
    float*       out  = (float*)d_out;

    const int n_thr = N_DIM * H_DIM * (W_DIM / 4);       // 262,144 pixel-threads
    const int block = 256;
    const int grid  = (n_thr / block) * C_GROUPS;        // 4096 blocks, 1D ONLY

    lcx_kernel<<<grid, block, 0, stream>>>(xyz, sm, mask, out);
}

// Round 5
// 226.125 us; speedup vs baseline: 1.1249x; 1.1249x over previous
//
#include <hip/hip_runtime.h>
#include <hip/hip_bf16.h>

// out[n,c,h,w] = sum_{5x5 in-bounds taps} exp(-0.5*||xyz_nbr - xyz_ctr||^2)
//                * mask_nbr * softmax[n,c,nbr]
// Zero-padded softmax => OOB taps contribute 0. We clamp OOB addresses and
// force their weights to 0 (finite garbage * 0.0f is safe).
//
// R5: LDS weight sharing. Block = 256 threads = 256 consecutive pixels of one
// row. Phase 1: thread t computes pixel t's 25 Gaussian weights once (R4
// recomputed them 4x, one per channel-group) -> LDS [25][256]. Phase 2:
// wave = channel-group (uniform), lane = pixel-quad; weights via
// conflict-free ds_read_b128, softmax windows via f2/f4/f2 vector loads.
// 1D grid ONLY (2D gridDim.y broke the harness graph replay in R3).

#define H_DIM 64
#define W_DIM 2048
#define C_DIM 20
#define N_DIM 8
#define HW (H_DIM * W_DIM)
#define BLOCK 256

__global__ __launch_bounds__(BLOCK) void lcx_kernel(
    const float* __restrict__ xyz,
    const float* __restrict__ sm,
    const int*  __restrict__ mask,
    float* __restrict__ out)
{
    __shared__ float w_lds[25 * BLOCK];   // [tap][pixel], 25.6 KB

    const int b  = blockIdx.x;            // 4096 blocks: 8 wchunks x 64 h x 8 n
    const int wc = b & 7;
    const int h  = (b >> 3) & (H_DIM - 1);
    const int n  = b >> 9;
    const int w0 = wc << 8;               // 256-pixel chunk base
    const int t  = threadIdx.x;

    const float* xyzn  = xyz  + (size_t)n * 3 * HW;
    const int*   maskn = mask + (size_t)n * HW;

    // ---------------- Phase 1: weights for pixel (h, w0+t) ----------------
    {
        const int px  = w0 + t;
        const int ctr = h * W_DIM + px;
        const float cx = xyzn[0 * HW + ctr];
        const float cy = xyzn[1 * HW + ctr];
        const float cz = xyzn[2 * HW + ctr];

        #pragma unroll
        for (int r = 0; r < 5; ++r) {
            const int hi  = h + r - 2;
            const bool rok = ((unsigned)hi < (unsigned)H_DIM);
            const int hic = rok ? hi : (hi < 0 ? 0 : H_DIM - 1);
            const int rbc = hic * W_DIM;
            #pragma unroll
            for (int dj = 0; dj < 5; ++dj) {
                const int col = px + dj - 2;
                const bool cok = ((unsigned)col < (unsigned)W_DIM);
                const int cc  = cok ? col : (col < 0 ? 0 : W_DIM - 1);
                const int o   = rbc + cc;
                const float xv = xyzn[0 * HW + o];
                const float yv = xyzn[1 * HW + o];
                const float zv = xyzn[2 * HW + o];
                const int   mv = maskn[o];
                const float dx = xv - cx;
                const float dy = yv - cy;
                const float dz = zv - cz;
                const float d2 = fmaf(dx, dx, fmaf(dy, dy, dz * dz));
                const bool ok = rok && cok && (mv != 0);
                w_lds[(r * 5 + dj) * BLOCK + t] = ok ? __expf(-0.5f * d2) : 0.0f;
            }
        }
    }
    __syncthreads();

    // ---------------- Phase 2: 4 pixels x 5 channels per thread ----------------
    const int cg = t >> 6;                // 0..3, wave-uniform channel group
    const int q  = t & 63;                // pixel-quad within chunk
    const int wq = w0 + (q << 2);         // base col of this thread's 4 pixels

    const float* smn  = sm  + ((size_t)n * C_DIM + cg * 5) * HW;
    float*       outn = out + ((size_t)n * C_DIM + cg * 5) * HW;

    // clamped column bases; columns covered: [wq-2 .. wq+5]
    const int b0 = (wq >= 2) ? (wq - 2) : 0;                        // float2
    const int b1 = wq;                                              // float4
    const int b2 = (wq + 4 <= W_DIM - 2) ? (wq + 4) : (W_DIM - 2);  // float2

    float4 acc[5];
    #pragma unroll
    for (int c = 0; c < 5; ++c) acc[c] = make_float4(0.f, 0.f, 0.f, 0.f);

    #pragma unroll
    for (int r = 0; r < 5; ++r) {
        const int hi  = h + r - 2;
        const int hic = (hi < 0) ? 0 : (hi >= H_DIM ? H_DIM - 1 : hi);
        const int rbc = hic * W_DIM;      // weights are 0 for OOB rows

        // 5 taps x 4 pixels of weights, conflict-free b128 reads
        float4 wt[5];
        #pragma unroll
        for (int dj = 0; dj < 5; ++dj)
            wt[dj] = *(const float4*)&w_lds[(r * 5 + dj) * BLOCK + (q << 2)];

        #pragma unroll
        for (int c = 0; c < 5; ++c) {
            const float* pr = smn + (size_t)c * HW + rbc;
            const float2 f0 = *(const float2*)(pr + b0);
            const float4 f1 = *(const float4*)(pr + b1);
            const float2 f2 = *(const float2*)(pr + b2);
            float fs[8];
            fs[0]=f0.x; fs[1]=f0.y; fs[2]=f1.x; fs[3]=f1.y;
            fs[4]=f1.z; fs[5]=f1.w; fs[6]=f2.x; fs[7]=f2.y;

            #pragma unroll
            for (int dj = 0; dj < 5; ++dj) {
                acc[c].x = fmaf(wt[dj].x, fs[0 + dj], acc[c].x);
                acc[c].y = fmaf(wt[dj].y, fs[1 + dj], acc[c].y);
                acc[c].z = fmaf(wt[dj].z, fs[2 + dj], acc[c].z);
                acc[c].w = fmaf(wt[dj].w, fs[3 + dj], acc[c].w);
            }
        }
    }

    const int octr = h * W_DIM + wq;
    #pragma unroll
    for (int c = 0; c < 5; ++c)
        *(float4*)(outn + (size_t)c * HW + octr) = acc[c];
}

extern "C" void kernel_launch(void* const* d_in, const int* in_sizes, int n_in,
                              void* d_out, int out_size, void* d_ws, size_t ws_size,
                              hipStream_t stream)
{
    const float* xyz  = (const float*)d_in[0];
    const float* sm   = (const float*)d_in[1];
    const int*   mask = (const int*)d_in[2];
    float*       out  = (float*)d_out;

    const int grid = 8 * H_DIM * N_DIM;   // 4096 blocks, 1D ONLY

    lcx_kernel<<<grid, BLOCK, 0, stream>>>(xyz, sm, mask, out);
}